// Round 7
// baseline (196.290 us; speedup 1.0000x reference)
//
#include <hip/hip_runtime.h>
#include <math.h>

#define NN 256
#define XX 256
#define TT 3
#define KK 64
#define AA 193          // 3*K+1
#define EPSF 1e-9f
#define NPART 256
#define SBLK 2048       // stream blocks
#define PBLK 2048       // pairs blocks (8 per n)
#define NBLK (SBLK + PBLK)

// ws layout (bytes):
// [0, 2048)            double part[256]
// [2048, 3072)         int nsel[256]
// [3072, 4096)         int ncols[256]
// [4096, 266240)       int S[256][256]      (full `order` per n)
// [266240, 331776)     int Ck[256][64]      (full `corder` per n)
// [331776, 1118208)    float mask[196608]   (gt_class value per row, 0.0/1.0)
// [1118208, 1118212)   int ticket

typedef float float4a __attribute__((ext_vector_type(4)));

__device__ __forceinline__ float4a ld4(const float* p) {
    float4a v;
    __builtin_memcpy(&v, p, 16);   // align-4 safe
    return v;
}

__global__ __launch_bounds__(256) void k_meta(const float* __restrict__ gt,
                                              int* __restrict__ nselArr,
                                              int* __restrict__ ncolsArr,
                                              int* __restrict__ S,
                                              int* __restrict__ Ck,
                                              double* __restrict__ part,
                                              float* __restrict__ mask,
                                              int* __restrict__ ticket) {
    int n = blockIdx.x;
    int tid = threadIdx.x;
    int lane = tid & 63;
    int wave = tid >> 6;

    // zero accumulators for this call (consumers launch after us on the stream)
    if (n == 0) {
        part[tid] = 0.0;
        if (tid == 0) *ticket = 0;
    }

    __shared__ int s_S[XX];
    __shared__ int s_cnt[4];
    __shared__ float s_red[256];
    __shared__ int s_nsel;

    // ---- phase 1: sel + stable partition (the `order` array) + row mask ----
    int x = tid;
    size_t rb = ((size_t)(n * XX + x) * TT) * AA;
    float gc0 = gt[rb + 3 * KK];
    float gc1 = gt[rb + AA + 3 * KK];
    float gc2 = gt[rb + 2 * AA + 3 * KK];
    int rowid = (n * XX + x) * TT;
    mask[rowid + 0] = gc0;
    mask[rowid + 1] = gc1;
    mask[rowid + 2] = gc2;

    bool selx = gc0 > 0.0f;
    unsigned long long bal = __ballot(selx);
    if (lane == 0) s_cnt[wave] = __popcll(bal);
    __syncthreads();
    int c0 = s_cnt[0], c1 = s_cnt[1], c2 = s_cnt[2], c3 = s_cnt[3];
    int nsel_n = c0 + c1 + c2 + c3;
    int selbase = (wave > 0 ? c0 : 0) + (wave > 1 ? c1 : 0) + (wave > 2 ? c2 : 0);
    unsigned long long ltmask = (1ull << lane) - 1ull;
    int pos;
    if (selx) pos = selbase + __popcll(bal & ltmask);
    else      pos = nsel_n + (64 * wave - selbase) + __popcll((~bal) & ltmask);
    s_S[pos] = x;
    if (tid == 0) { s_nsel = nsel_n; nselArr[n] = nsel_n; }
    __syncthreads();
    S[n * XX + tid] = s_S[tid];

    // ---- phase 2: column sums over selected rows ----
    int nsl = s_nsel;
    float partial = 0.0f;
    for (int i = wave; i < nsl; i += 4) {
        int xs = s_S[i];
        size_t base = ((size_t)(n * XX + xs) * TT) * AA + 2 * KK + lane;
        partial += gt[base] + gt[base + AA] + gt[base + 2 * AA];
    }
    s_red[tid] = partial;
    __syncthreads();

    // ---- phase 3: keep + stable column partition (the `corder` array) ----
    if (tid < KK) {
        float tot = s_red[tid] + s_red[tid + 64] + s_red[tid + 128] + s_red[tid + 192];
        int nrows = nsl * TT;
        bool keep = (tot >= (float)nrows) || (tid < 5);
        unsigned long long kb = __ballot(keep);
        int nc = __popcll(kb);
        unsigned long long lt = (1ull << tid) - 1ull;
        int cpos = keep ? __popcll(kb & lt) : nc + __popcll((~kb) & lt);
        Ck[n * KK + cpos] = tid;
        if (tid == 0) ncolsArr[n] = nc;
    }
}

// Spatially-partitioned fused kernel: even blocks stream (loss0/1/2, BW-bound),
// odd blocks do pairs (loss3/4, latency-bound). Both roles co-resident on every
// CU -> pairs gathers hide in the stream waves' memory-latency slack.
// Last block (ticket) folds part[] into out[0].
__global__ __launch_bounds__(256) void k_fused(const float* __restrict__ pred,
                                               const float* __restrict__ gt,
                                               const float* __restrict__ mask,
                                               const float* __restrict__ hcam_arr,
                                               const float* __restrict__ ax,
                                               const float* __restrict__ ay,
                                               const float* __restrict__ xstd,
                                               const float* __restrict__ zstd,
                                               const int* __restrict__ nselArr,
                                               const int* __restrict__ ncolsArr,
                                               const int* __restrict__ S,
                                               const int* __restrict__ Ck,
                                               double* __restrict__ part,
                                               int* __restrict__ ticket,
                                               float* __restrict__ out) {
    int tid = threadIdx.x;
    int lane = tid & 63;
    int wid = tid >> 6;
    int role_pairs = blockIdx.x & 1;
    int idx = blockIdx.x >> 1;          // 0..2047 within each role

    float local = 0.0f;

    if (role_pairs) {
        // ---- pairs role: 8 blocks per n, 32 waves per n ----
        float accp = 0.0f;
        int n = idx >> 3;
        int waveIdx = ((idx & 7) << 2) | wid;          // 0..31
        int nrows = nselArr[n] * TT;
        int ncols = ncolsArr[n];
        int k = Ck[n * KK + lane];
        float inv_h = 1.0f / hcam_arr[n];
        float zs = zstd[k], xs = xstd[k], ayk = ay[k];
        float xstd0 = xstd[0];

        for (int i = 0; i < 24; ++i) {
            int p = i * 32 + waveIdx;                  // covers 0..767
            if (p + 1 >= nrows) break;                 // wave-uniform, monotone
            int r1 = p + 1;
            int x0 = S[n * XX + p / 3];  int t0 = p % 3;
            int x1 = S[n * XX + r1 / 3]; int t1 = r1 % 3;
            size_t b0 = ((size_t)(n * XX + x0) * TT + t0) * AA;
            size_t b1 = ((size_t)(n * XX + x1) * TT + t1) * AA;
            float pz0 = pred[b0 + KK + k], gx0 = gt[b0 + k];
            float pz1 = pred[b1 + KK + k], gx1 = gt[b1 + k];
            float ax0 = ax[x0], ax1 = ax[x1];
            float Z0 = pz0 * zs, Z1 = pz1 * zs;
            float sc0 = 1.0f - Z0 * inv_h, sc1 = 1.0f - Z1 * inv_h;
            float L0 = sc0 * (gx0 * xs + ax0);
            float L1 = sc1 * (gx1 * xs + ax1);
            float Y0 = sc0 * ayk;
            float l00 = gt[b0] * xstd0 + ax0;
            float l01 = gt[b1] * xstd0 + ax1;
            float width0 = fabsf(l01 - l00);

            float lm1 = __shfl_up(L0, 1);
            float ym1 = __shfl_up(Y0, 1);
            float y1v = __shfl(Y0, 1);
            float dYc, lc;
            if (lane == 0) {
                dYc = fabsf(y1v - Y0);
                lc = dYc;
            } else {
                dYc = fabsf(Y0 - ym1);
                float dx = L0 - lm1;
                lc = sqrtf(dx * dx + dYc * dYc);
            }
            float w = fabsf(L1 - L0) * dYc / (lc + EPSF);
            float wm1 = __shfl_up(w, 1);
            float werr = fabsf(w - (lane == 0 ? width0 : wm1));
            float dZ = fabsf(Z1 - Z0);
            if (lane < ncols) accp += werr + dZ;
        }
        local = 5.0f * accp;
    } else {
        // ---- stream role: loss0 + loss1 + loss2 ----
        float a0 = 0.0f, a12 = 0.0f;
        int sub = lane & 15;        // 16-B chunk within the 256-B field
        int rr = lane >> 4;         // row within group of 4
        int gw = idx * 4 + wid;
        const int NW = SBLK * 4;
        const int NGROUP = NN * XX * TT / 4;   // 49152 = 8192 waves * 6

        #pragma unroll 2
        for (int g = gw; g < NGROUP; g += NW) {
            int row = 4 * g + rr;
            size_t base = (size_t)row * AA;
            float mi = mask[row];                       // L2-hot, 0.0 or 1.0
            float4a pv = ld4(pred + base + 2 * KK + sub * 4);
            float4a gv = ld4(gt   + base + 2 * KK + sub * 4);
            float pc = pred[base + 3 * KK];

            a0 += __logf(gv.x > 0.0f ? pv.x + EPSF : 1.0f - pv.x + EPSF)
                + __logf(gv.y > 0.0f ? pv.y + EPSF : 1.0f - pv.y + EPSF)
                + __logf(gv.z > 0.0f ? pv.z + EPSF : 1.0f - pv.z + EPSF)
                + __logf(gv.w > 0.0f ? pv.w + EPSF : 1.0f - pv.w + EPSF);

            if (sub == 0)
                a12 -= __logf(mi > 0.0f ? pc + EPSF : 1.0f - pc + EPSF);

            if (mi > 0.0f) {                            // exec-masked: no lines
                float4a pX = ld4(pred + base + sub * 4);
                float4a gX = ld4(gt   + base + sub * 4);
                a12 += gv.x * fabsf(pX.x - gX.x) + gv.y * fabsf(pX.y - gX.y)
                     + gv.z * fabsf(pX.z - gX.z) + gv.w * fabsf(pX.w - gX.w);
            }
        }
        local = a12 - a0 * (1.0f / KK);
    }

    // ---- reduce + last-block final ----
    __shared__ float red[256];
    red[tid] = local;
    __syncthreads();
    for (int s = 128; s > 0; s >>= 1) {
        if (tid < s) red[tid] += red[tid + s];
        __syncthreads();
    }

    __shared__ int s_last;
    if (tid == 0) {
        atomicAdd(&part[blockIdx.x & (NPART - 1)], (double)red[0]);
        __threadfence();
        int t = atomicAdd(ticket, 1);
        s_last = (t == NBLK - 1) ? 1 : 0;
    }
    __syncthreads();

    if (s_last) {
        __threadfence();
        double v = __hip_atomic_load(&part[tid], __ATOMIC_RELAXED,
                                     __HIP_MEMORY_SCOPE_AGENT);
        __shared__ double dred[256];
        dred[tid] = v;
        __syncthreads();
        for (int s = 128; s > 0; s >>= 1) {
            if (tid < s) dred[tid] += dred[tid + s];
            __syncthreads();
        }
        if (tid == 0) out[0] = (float)dred[0];
    }
}

extern "C" void kernel_launch(void* const* d_in, const int* in_sizes, int n_in,
                              void* d_out, int out_size, void* d_ws, size_t ws_size,
                              hipStream_t stream) {
    const float* pred = (const float*)d_in[0];
    const float* gt   = (const float*)d_in[1];
    const float* hcam = (const float*)d_in[2];
    const float* ax   = (const float*)d_in[3];
    const float* ay   = (const float*)d_in[4];
    const float* xstd = (const float*)d_in[5];
    const float* zstd = (const float*)d_in[6];
    float* out = (float*)d_out;

    char* ws = (char*)d_ws;
    double* part = (double*)ws;
    int* nsel   = (int*)(ws + 2048);
    int* ncols  = (int*)(ws + 3072);
    int* S      = (int*)(ws + 4096);
    int* Ck     = (int*)(ws + 266240);
    float* mask = (float*)(ws + 331776);
    int* ticket = (int*)(ws + 1118208);

    hipLaunchKernelGGL(k_meta, dim3(NN), dim3(256), 0, stream,
                       gt, nsel, ncols, S, Ck, part, mask, ticket);
    hipLaunchKernelGGL(k_fused, dim3(NBLK), dim3(256), 0, stream,
                       pred, gt, mask, hcam, ax, ay, xstd, zstd,
                       nsel, ncols, S, Ck, part, ticket, out);
}

// Round 8
// 74.292 us; speedup vs baseline: 2.6421x; 2.6421x over previous
//
#include <hip/hip_runtime.h>
#include <math.h>

#define NN 256
#define XX 256
#define TT 3
#define KK 64
#define AA 193          // 3*K+1
#define EPSF 1e-9f
#define NPART 256
#define WPB 4           // waves per block in k_pairs
#define ITER 4          // consecutive pairs per wave in k_pairs
#define PB 48           // blocks per n in k_pairs: 48*4*4 = 768 >= 767

// ws layout (bytes):
// [0, 2048)         double part[256]
// [2048, 3072)      int nsel[256]
// [3072, 4096)      int ncols[256]
// [4096, 266240)    int S[256][256]   (full `order` per n)
// [266240, 331776)  int Ck[256][64]   (full `corder` per n)

typedef float float4a __attribute__((ext_vector_type(4)));

__device__ __forceinline__ float4a ld4(const float* p) {
    float4a v;
    __builtin_memcpy(&v, p, 16);   // align-4 safe
    return v;
}

// 1024 threads: phase 1 runs on first 4 waves, phase 2 on all 16 waves.
__global__ __launch_bounds__(1024) void k_meta(const float* __restrict__ gt,
                                               int* __restrict__ nselArr,
                                               int* __restrict__ ncolsArr,
                                               int* __restrict__ S,
                                               int* __restrict__ Ck,
                                               double* __restrict__ part) {
    int n = blockIdx.x;
    int tid = threadIdx.x;
    int lane = tid & 63;
    int wave = tid >> 6;

    // zero the partial-sum buffer (consumers launch after us on the stream)
    if (n == 0 && tid < NPART) part[tid] = 0.0;

    __shared__ int s_S[XX];
    __shared__ int s_cnt[4];
    __shared__ float s_red[16 * 64];
    __shared__ int s_nsel;

    // ---- phase 1: sel + stable partition (the `order` array) ----
    if (tid < XX) {
        int x = tid;
        float gc = gt[((size_t)(n * XX + x) * TT + 0) * AA + (AA - 1)];
        bool selx = gc > 0.0f;
        unsigned long long bal = __ballot(selx);
        if (lane == 0) s_cnt[wave] = __popcll(bal);
        // positions resolved after barrier
        __syncthreads();
        int c0 = s_cnt[0], c1 = s_cnt[1], c2 = s_cnt[2], c3 = s_cnt[3];
        int nsel_n = c0 + c1 + c2 + c3;
        int selbase = (wave > 0 ? c0 : 0) + (wave > 1 ? c1 : 0) + (wave > 2 ? c2 : 0);
        unsigned long long ltmask = (1ull << lane) - 1ull;
        int pos;
        if (selx) pos = selbase + __popcll(bal & ltmask);
        else      pos = nsel_n + (64 * wave - selbase) + __popcll((~bal) & ltmask);
        s_S[pos] = x;
        if (tid == 0) { s_nsel = nsel_n; nselArr[n] = nsel_n; }
    } else {
        __syncthreads();
    }
    __syncthreads();
    if (tid < XX) S[n * XX + tid] = s_S[tid];

    // ---- phase 2: column sums over selected rows (16 waves) ----
    int nsl = s_nsel;
    float partial = 0.0f;
    for (int i = wave; i < nsl; i += 16) {
        int xs = s_S[i];
        size_t base = ((size_t)(n * XX + xs) * TT) * AA + 2 * KK + lane;
        partial += gt[base] + gt[base + AA] + gt[base + 2 * AA];
    }
    s_red[tid] = partial;
    __syncthreads();

    // ---- phase 3: keep + stable column partition (the `corder` array) ----
    if (tid < KK) {
        float tot = 0.0f;
        #pragma unroll
        for (int w = 0; w < 16; ++w) tot += s_red[tid + 64 * w];
        int nrows = nsl * TT;
        bool keep = (tot >= (float)nrows) || (tid < 5);
        unsigned long long kb = __ballot(keep);
        int nc = __popcll(kb);
        unsigned long long lt = (1ull << tid) - 1ull;
        int cpos = keep ? __popcll(kb & lt) : nc + __popcll((~kb) & lt);
        Ck[n * KK + cpos] = tid;
        if (tid == 0) ncolsArr[n] = nc;
    }
}

// Fused streaming pass: loss0 (vis BCE), loss1 (cls BCE), loss2 (xoff L1).
// Lane = (chunk sub=l&15, row rr=l>>4); float4 per lane; 4 rows per group.
// 49152 groups = 8192 waves * 6; processed as 3 halves of 2 groups with all
// loads batched up-front (>=160B/lane in flight). gc/pc ride the lines the
// gv/pv field loads already fetched (row stride 772B => shared for 15/16 rows).
__global__ __launch_bounds__(256, 8) void k_main(const float* __restrict__ pred,
                                                 const float* __restrict__ gt,
                                                 double* __restrict__ part) {
    int tid = threadIdx.x;
    int lane = tid & 63;
    int sub = lane & 15;        // 16-B chunk within the 256-B field
    int rr = lane >> 4;         // row within group of 4
    int gw = blockIdx.x * 4 + (tid >> 6);
    const int NW = 2048 * 4;

    float a0 = 0.0f, a12 = 0.0f;
    #pragma unroll
    for (int half = 0; half < 3; ++half) {
        int g0 = gw + (2 * half) * NW;
        int g1 = g0 + NW;
        size_t b0 = (size_t)(4 * g0 + rr) * AA;
        size_t b1 = (size_t)(4 * g1 + rr) * AA;

        // batch all unconditional loads for both groups
        float4a pv0 = ld4(pred + b0 + 2 * KK + sub * 4);
        float4a gv0 = ld4(gt   + b0 + 2 * KK + sub * 4);
        float4a pv1 = ld4(pred + b1 + 2 * KK + sub * 4);
        float4a gv1 = ld4(gt   + b1 + 2 * KK + sub * 4);
        float gc0 = gt[b0 + 3 * KK];
        float gc1 = gt[b1 + 3 * KK];
        float pc0 = pred[b0 + 3 * KK];
        float pc1 = pred[b1 + 3 * KK];

        // issue predicated xoff loads before the log computation
        bool m0 = gc0 > 0.0f, m1 = gc1 > 0.0f;
        float4a pX0 = {0,0,0,0}, gX0 = {0,0,0,0}, pX1 = {0,0,0,0}, gX1 = {0,0,0,0};
        if (m0) { pX0 = ld4(pred + b0 + sub * 4); gX0 = ld4(gt + b0 + sub * 4); }
        if (m1) { pX1 = ld4(pred + b1 + sub * 4); gX1 = ld4(gt + b1 + sub * 4); }

        a0 += __logf(gv0.x > 0.0f ? pv0.x + EPSF : 1.0f - pv0.x + EPSF)
            + __logf(gv0.y > 0.0f ? pv0.y + EPSF : 1.0f - pv0.y + EPSF)
            + __logf(gv0.z > 0.0f ? pv0.z + EPSF : 1.0f - pv0.z + EPSF)
            + __logf(gv0.w > 0.0f ? pv0.w + EPSF : 1.0f - pv0.w + EPSF)
            + __logf(gv1.x > 0.0f ? pv1.x + EPSF : 1.0f - pv1.x + EPSF)
            + __logf(gv1.y > 0.0f ? pv1.y + EPSF : 1.0f - pv1.y + EPSF)
            + __logf(gv1.z > 0.0f ? pv1.z + EPSF : 1.0f - pv1.z + EPSF)
            + __logf(gv1.w > 0.0f ? pv1.w + EPSF : 1.0f - pv1.w + EPSF);

        if (sub == 0) {
            a12 -= __logf(m0 ? pc0 + EPSF : 1.0f - pc0 + EPSF);
            a12 -= __logf(m1 ? pc1 + EPSF : 1.0f - pc1 + EPSF);
        }

        if (m0)
            a12 += gv0.x * fabsf(pX0.x - gX0.x) + gv0.y * fabsf(pX0.y - gX0.y)
                 + gv0.z * fabsf(pX0.z - gX0.z) + gv0.w * fabsf(pX0.w - gX0.w);
        if (m1)
            a12 += gv1.x * fabsf(pX1.x - gX1.x) + gv1.y * fabsf(pX1.y - gX1.y)
                 + gv1.z * fabsf(pX1.z - gX1.z) + gv1.w * fabsf(pX1.w - gX1.w);
    }
    float local = a12 - a0 * (1.0f / KK);

    __shared__ float red[256];
    red[tid] = local;
    __syncthreads();
    for (int s = 128; s > 0; s >>= 1) {
        if (tid < s) red[tid] += red[tid + s];
        __syncthreads();
    }
    if (tid == 0) atomicAdd(&part[blockIdx.x & (NPART - 1)], (double)red[0]);
}

__global__ __launch_bounds__(256) void k_pairs(const float* __restrict__ pred,
                                               const float* __restrict__ gt,
                                               const float* __restrict__ hcam_arr,
                                               const float* __restrict__ ax,
                                               const float* __restrict__ ay,
                                               const float* __restrict__ xstd,
                                               const float* __restrict__ zstd,
                                               const int* __restrict__ nselArr,
                                               const int* __restrict__ ncolsArr,
                                               const int* __restrict__ S,
                                               const int* __restrict__ Ck,
                                               double* __restrict__ part) {
    int n = blockIdx.x / PB;
    int chunk = blockIdx.x % PB;
    int tid = threadIdx.x;
    int lane = tid & 63;
    int wid = tid >> 6;

    int nsl = nselArr[n];
    int nrows = nsl * TT;
    int ncols = ncolsArr[n];
    int k = Ck[n * KK + lane];
    float inv_h = 1.0f / hcam_arr[n];
    float zs = zstd[k], xs = xstd[k], ayk = ay[k];
    float xstd0 = xstd[0];

    float acc = 0.0f;
    for (int i = 0; i < ITER; ++i) {
        int p = chunk * (WPB * ITER) + wid * ITER + i;
        if (p + 1 >= nrows) continue;
        int r1 = p + 1;
        int x0 = S[n * XX + p / 3];  int t0 = p % 3;
        int x1 = S[n * XX + r1 / 3]; int t1 = r1 % 3;
        size_t b0 = ((size_t)(n * XX + x0) * TT + t0) * AA;
        size_t b1 = ((size_t)(n * XX + x1) * TT + t1) * AA;
        float pz0 = pred[b0 + KK + k], gx0 = gt[b0 + k];
        float pz1 = pred[b1 + KK + k], gx1 = gt[b1 + k];
        float ax0 = ax[x0], ax1 = ax[x1];
        float Z0 = pz0 * zs, Z1 = pz1 * zs;
        float sc0 = 1.0f - Z0 * inv_h, sc1 = 1.0f - Z1 * inv_h;
        float L0 = sc0 * (gx0 * xs + ax0);
        float L1 = sc1 * (gx1 * xs + ax1);
        float Y0 = sc0 * ayk;
        float l00 = gt[b0] * xstd0 + ax0;
        float l01 = gt[b1] * xstd0 + ax1;
        float width0 = fabsf(l01 - l00);

        float lm1 = __shfl_up(L0, 1);
        float ym1 = __shfl_up(Y0, 1);
        float y1v = __shfl(Y0, 1);
        float dYc, lc;
        if (lane == 0) {
            dYc = fabsf(y1v - Y0);
            lc = dYc;
        } else {
            dYc = fabsf(Y0 - ym1);
            float dx = L0 - lm1;
            lc = sqrtf(dx * dx + dYc * dYc);
        }
        float w = fabsf(L1 - L0) * dYc / (lc + EPSF);
        float wm1 = __shfl_up(w, 1);
        float werr = fabsf(w - (lane == 0 ? width0 : wm1));
        float dZ = fabsf(Z1 - Z0);
        if (lane < ncols) acc += werr + dZ;
    }

    __shared__ float red[256];
    red[tid] = acc;
    __syncthreads();
    for (int s = 128; s > 0; s >>= 1) {
        if (tid < s) red[tid] += red[tid + s];
        __syncthreads();
    }
    if (tid == 0 && red[0] != 0.0f)
        atomicAdd(&part[blockIdx.x & (NPART - 1)], (double)(5.0f * red[0]));
}

__global__ __launch_bounds__(256) void k_final(const double* __restrict__ part,
                                               float* __restrict__ out) {
    int tid = threadIdx.x;
    __shared__ double red[256];
    red[tid] = part[tid];
    __syncthreads();
    for (int s = 128; s > 0; s >>= 1) {
        if (tid < s) red[tid] += red[tid + s];
        __syncthreads();
    }
    if (tid == 0) out[0] = (float)red[0];
}

extern "C" void kernel_launch(void* const* d_in, const int* in_sizes, int n_in,
                              void* d_out, int out_size, void* d_ws, size_t ws_size,
                              hipStream_t stream) {
    const float* pred = (const float*)d_in[0];
    const float* gt   = (const float*)d_in[1];
    const float* hcam = (const float*)d_in[2];
    const float* ax   = (const float*)d_in[3];
    const float* ay   = (const float*)d_in[4];
    const float* xstd = (const float*)d_in[5];
    const float* zstd = (const float*)d_in[6];
    float* out = (float*)d_out;

    char* ws = (char*)d_ws;
    double* part = (double*)ws;
    int* nsel  = (int*)(ws + 2048);
    int* ncols = (int*)(ws + 3072);
    int* S     = (int*)(ws + 4096);
    int* Ck    = (int*)(ws + 266240);

    hipLaunchKernelGGL(k_meta, dim3(NN), dim3(1024), 0, stream,
                       gt, nsel, ncols, S, Ck, part);
    hipLaunchKernelGGL(k_main, dim3(2048), dim3(256), 0, stream, pred, gt, part);
    hipLaunchKernelGGL(k_pairs, dim3(NN * PB), dim3(256), 0, stream,
                       pred, gt, hcam, ax, ay, xstd, zstd, nsel, ncols, S, Ck, part);
    hipLaunchKernelGGL(k_final, dim3(1), dim3(256), 0, stream, part, out);
}

// Round 9
// 64.379 us; speedup vs baseline: 3.0490x; 1.1540x over previous
//
#include <hip/hip_runtime.h>
#include <math.h>

#define NN 256
#define XX 256
#define TT 3
#define KK 64
#define AA 193          // 3*K+1
#define EPSF 1e-9f
#define NPART 256
#define WPB 4           // waves per block in k_pairs
#define ITER 4          // consecutive pairs per wave in k_pairs
#define PB 48           // blocks per n in k_pairs: 48*4*4 = 768 >= 767

// ws layout (bytes):
// [0, 2048)            double part[256]
// [2048, 3072)         int nsel[256]
// [3072, 4096)         int ncols[256]
// [4096, 266240)       int S[256][256]      (full `order` per n)
// [266240, 331776)     int Ck[256][64]      (full `corder` per n)
// [331776, 1118208)    float mask[196608]   (gt_class value per row, 0.0/1.0)

typedef float float4a __attribute__((ext_vector_type(4)));

__device__ __forceinline__ float4a ld4(const float* p) {
    float4a v;
    __builtin_memcpy(&v, p, 16);   // align-4 safe
    return v;
}

// 1024 threads: phase 1 on waves 0-3 (one x per thread), phase 2 on all 16 waves.
__global__ __launch_bounds__(1024) void k_meta(const float* __restrict__ gt,
                                               int* __restrict__ nselArr,
                                               int* __restrict__ ncolsArr,
                                               int* __restrict__ S,
                                               int* __restrict__ Ck,
                                               double* __restrict__ part,
                                               float* __restrict__ mask) {
    int n = blockIdx.x;
    int tid = threadIdx.x;
    int lane = tid & 63;
    int wave = tid >> 6;
    bool isP1 = wave < 4;          // tid < 256, wave-uniform

    // zero the partial-sum buffer (consumers launch after us on the stream)
    if (n == 0 && tid < NPART) part[tid] = 0.0;

    __shared__ int s_S[XX];
    __shared__ int s_cnt[4];
    __shared__ float s_red[16 * 64];
    __shared__ int s_nsel;

    // ---- phase 1a: load gc, write mask, ballot ----
    bool selx = false;
    unsigned long long bal = 0;
    if (isP1) {
        int x = tid;
        size_t rb = ((size_t)(n * XX + x) * TT) * AA;
        float gc0 = gt[rb + 3 * KK];
        float gc1 = gt[rb + AA + 3 * KK];
        float gc2 = gt[rb + 2 * AA + 3 * KK];
        int rowid = (n * XX + x) * TT;
        mask[rowid + 0] = gc0;
        mask[rowid + 1] = gc1;
        mask[rowid + 2] = gc2;
        selx = gc0 > 0.0f;
        bal = __ballot(selx);
        if (lane == 0) s_cnt[wave] = __popcll(bal);
    }
    __syncthreads();

    // ---- phase 1b: stable partition (the `order` array) ----
    if (isP1) {
        int c0 = s_cnt[0], c1 = s_cnt[1], c2 = s_cnt[2], c3 = s_cnt[3];
        int nsel_n = c0 + c1 + c2 + c3;
        int selbase = (wave > 0 ? c0 : 0) + (wave > 1 ? c1 : 0) + (wave > 2 ? c2 : 0);
        unsigned long long ltmask = (1ull << lane) - 1ull;
        int pos;
        if (selx) pos = selbase + __popcll(bal & ltmask);
        else      pos = nsel_n + (64 * wave - selbase) + __popcll((~bal) & ltmask);
        s_S[pos] = tid;
        if (tid == 0) { s_nsel = nsel_n; nselArr[n] = nsel_n; }
    }
    __syncthreads();
    if (tid < XX) S[n * XX + tid] = s_S[tid];

    // ---- phase 2: column sums over selected rows (16 waves) ----
    int nsl = s_nsel;
    float partial = 0.0f;
    for (int i = wave; i < nsl; i += 16) {
        int xs = s_S[i];
        size_t base = ((size_t)(n * XX + xs) * TT) * AA + 2 * KK + lane;
        partial += gt[base] + gt[base + AA] + gt[base + 2 * AA];
    }
    s_red[tid] = partial;
    __syncthreads();

    // ---- phase 3: keep + stable column partition (the `corder` array) ----
    if (tid < KK) {
        float tot = 0.0f;
        #pragma unroll
        for (int w = 0; w < 16; ++w) tot += s_red[tid + 64 * w];
        int nrows = nsl * TT;
        bool keep = (tot >= (float)nrows) || (tid < 5);
        unsigned long long kb = __ballot(keep);
        int nc = __popcll(kb);
        unsigned long long lt = (1ull << tid) - 1ull;
        int cpos = keep ? __popcll(kb & lt) : nc + __popcll((~kb) & lt);
        Ck[n * KK + cpos] = tid;
        if (tid == 0) ncolsArr[n] = nc;
    }
}

// Fused streaming pass: loss0 (vis BCE), loss1 (cls BCE), loss2 (xoff L1).
// Lane = (chunk sub=l&15, row rr=l>>4); float4 per lane; 4 rows per group.
// All 6 mask predicates pre-loaded (L2-hot) -> every VMEM op in a 2-group
// step issues with no dependent stall. No min-wave clamp: VGPRs free.
__global__ __launch_bounds__(256) void k_main(const float* __restrict__ pred,
                                              const float* __restrict__ gt,
                                              const float* __restrict__ mask,
                                              double* __restrict__ part) {
    int tid = threadIdx.x;
    int lane = tid & 63;
    int sub = lane & 15;        // 16-B chunk within the 256-B field
    int rr = lane >> 4;         // row within group of 4
    int gw = blockIdx.x * 4 + (tid >> 6);
    const int NW = 2048 * 4;

    // prefetch all 6 row-mask predicates (mask is 786 KB, L2-resident)
    float mk[6];
    #pragma unroll
    for (int j = 0; j < 6; ++j) mk[j] = mask[4 * (gw + j * NW) + rr];

    float a0 = 0.0f, a12 = 0.0f;
    #pragma unroll
    for (int h = 0; h < 3; ++h) {
        size_t b0 = (size_t)(4 * (gw + (2 * h) * NW) + rr) * AA;
        size_t b1 = (size_t)(4 * (gw + (2 * h + 1) * NW) + rr) * AA;
        bool m0 = mk[2 * h] > 0.0f, m1 = mk[2 * h + 1] > 0.0f;

        // batch: all loads for both groups issue back-to-back
        float4a pv0 = ld4(pred + b0 + 2 * KK + sub * 4);
        float4a gv0 = ld4(gt   + b0 + 2 * KK + sub * 4);
        float4a pv1 = ld4(pred + b1 + 2 * KK + sub * 4);
        float4a gv1 = ld4(gt   + b1 + 2 * KK + sub * 4);
        float pc0 = pred[b0 + 3 * KK];
        float pc1 = pred[b1 + 3 * KK];
        float4a pX0 = {0,0,0,0}, gX0 = {0,0,0,0}, pX1 = {0,0,0,0}, gX1 = {0,0,0,0};
        if (m0) { pX0 = ld4(pred + b0 + sub * 4); gX0 = ld4(gt + b0 + sub * 4); }
        if (m1) { pX1 = ld4(pred + b1 + sub * 4); gX1 = ld4(gt + b1 + sub * 4); }

        a0 += __logf(gv0.x > 0.0f ? pv0.x + EPSF : 1.0f - pv0.x + EPSF)
            + __logf(gv0.y > 0.0f ? pv0.y + EPSF : 1.0f - pv0.y + EPSF)
            + __logf(gv0.z > 0.0f ? pv0.z + EPSF : 1.0f - pv0.z + EPSF)
            + __logf(gv0.w > 0.0f ? pv0.w + EPSF : 1.0f - pv0.w + EPSF)
            + __logf(gv1.x > 0.0f ? pv1.x + EPSF : 1.0f - pv1.x + EPSF)
            + __logf(gv1.y > 0.0f ? pv1.y + EPSF : 1.0f - pv1.y + EPSF)
            + __logf(gv1.z > 0.0f ? pv1.z + EPSF : 1.0f - pv1.z + EPSF)
            + __logf(gv1.w > 0.0f ? pv1.w + EPSF : 1.0f - pv1.w + EPSF);

        if (sub == 0) {
            a12 -= __logf(m0 ? pc0 + EPSF : 1.0f - pc0 + EPSF);
            a12 -= __logf(m1 ? pc1 + EPSF : 1.0f - pc1 + EPSF);
        }

        if (m0)
            a12 += gv0.x * fabsf(pX0.x - gX0.x) + gv0.y * fabsf(pX0.y - gX0.y)
                 + gv0.z * fabsf(pX0.z - gX0.z) + gv0.w * fabsf(pX0.w - gX0.w);
        if (m1)
            a12 += gv1.x * fabsf(pX1.x - gX1.x) + gv1.y * fabsf(pX1.y - gX1.y)
                 + gv1.z * fabsf(pX1.z - gX1.z) + gv1.w * fabsf(pX1.w - gX1.w);
    }
    float local = a12 - a0 * (1.0f / KK);

    __shared__ float red[256];
    red[tid] = local;
    __syncthreads();
    for (int s = 128; s > 0; s >>= 1) {
        if (tid < s) red[tid] += red[tid + s];
        __syncthreads();
    }
    if (tid == 0) atomicAdd(&part[blockIdx.x & (NPART - 1)], (double)red[0]);
}

__global__ __launch_bounds__(256) void k_pairs(const float* __restrict__ pred,
                                               const float* __restrict__ gt,
                                               const float* __restrict__ hcam_arr,
                                               const float* __restrict__ ax,
                                               const float* __restrict__ ay,
                                               const float* __restrict__ xstd,
                                               const float* __restrict__ zstd,
                                               const int* __restrict__ nselArr,
                                               const int* __restrict__ ncolsArr,
                                               const int* __restrict__ S,
                                               const int* __restrict__ Ck,
                                               double* __restrict__ part) {
    int n = blockIdx.x / PB;
    int chunk = blockIdx.x % PB;
    int tid = threadIdx.x;
    int lane = tid & 63;
    int wid = tid >> 6;

    int nsl = nselArr[n];
    int nrows = nsl * TT;
    int ncols = ncolsArr[n];
    int k = Ck[n * KK + lane];
    float inv_h = 1.0f / hcam_arr[n];
    float zs = zstd[k], xs = xstd[k], ayk = ay[k];
    float xstd0 = xstd[0];

    float acc = 0.0f;
    for (int i = 0; i < ITER; ++i) {
        int p = chunk * (WPB * ITER) + wid * ITER + i;
        if (p + 1 >= nrows) continue;
        int r1 = p + 1;
        int x0 = S[n * XX + p / 3];  int t0 = p % 3;
        int x1 = S[n * XX + r1 / 3]; int t1 = r1 % 3;
        size_t b0 = ((size_t)(n * XX + x0) * TT + t0) * AA;
        size_t b1 = ((size_t)(n * XX + x1) * TT + t1) * AA;
        float pz0 = pred[b0 + KK + k], gx0 = gt[b0 + k];
        float pz1 = pred[b1 + KK + k], gx1 = gt[b1 + k];
        float ax0 = ax[x0], ax1 = ax[x1];
        float Z0 = pz0 * zs, Z1 = pz1 * zs;
        float sc0 = 1.0f - Z0 * inv_h, sc1 = 1.0f - Z1 * inv_h;
        float L0 = sc0 * (gx0 * xs + ax0);
        float L1 = sc1 * (gx1 * xs + ax1);
        float Y0 = sc0 * ayk;
        float l00 = gt[b0] * xstd0 + ax0;
        float l01 = gt[b1] * xstd0 + ax1;
        float width0 = fabsf(l01 - l00);

        float lm1 = __shfl_up(L0, 1);
        float ym1 = __shfl_up(Y0, 1);
        float y1v = __shfl(Y0, 1);
        float dYc, lc;
        if (lane == 0) {
            dYc = fabsf(y1v - Y0);
            lc = dYc;
        } else {
            dYc = fabsf(Y0 - ym1);
            float dx = L0 - lm1;
            lc = sqrtf(dx * dx + dYc * dYc);
        }
        float w = fabsf(L1 - L0) * dYc / (lc + EPSF);
        float wm1 = __shfl_up(w, 1);
        float werr = fabsf(w - (lane == 0 ? width0 : wm1));
        float dZ = fabsf(Z1 - Z0);
        if (lane < ncols) acc += werr + dZ;
    }

    __shared__ float red[256];
    red[tid] = acc;
    __syncthreads();
    for (int s = 128; s > 0; s >>= 1) {
        if (tid < s) red[tid] += red[tid + s];
        __syncthreads();
    }
    if (tid == 0 && red[0] != 0.0f)
        atomicAdd(&part[blockIdx.x & (NPART - 1)], (double)(5.0f * red[0]));
}

__global__ __launch_bounds__(256) void k_final(const double* __restrict__ part,
                                               float* __restrict__ out) {
    int tid = threadIdx.x;
    __shared__ double red[256];
    red[tid] = part[tid];
    __syncthreads();
    for (int s = 128; s > 0; s >>= 1) {
        if (tid < s) red[tid] += red[tid + s];
        __syncthreads();
    }
    if (tid == 0) out[0] = (float)red[0];
}

extern "C" void kernel_launch(void* const* d_in, const int* in_sizes, int n_in,
                              void* d_out, int out_size, void* d_ws, size_t ws_size,
                              hipStream_t stream) {
    const float* pred = (const float*)d_in[0];
    const float* gt   = (const float*)d_in[1];
    const float* hcam = (const float*)d_in[2];
    const float* ax   = (const float*)d_in[3];
    const float* ay   = (const float*)d_in[4];
    const float* xstd = (const float*)d_in[5];
    const float* zstd = (const float*)d_in[6];
    float* out = (float*)d_out;

    char* ws = (char*)d_ws;
    double* part = (double*)ws;
    int* nsel   = (int*)(ws + 2048);
    int* ncols  = (int*)(ws + 3072);
    int* S      = (int*)(ws + 4096);
    int* Ck     = (int*)(ws + 266240);
    float* mask = (float*)(ws + 331776);

    hipLaunchKernelGGL(k_meta, dim3(NN), dim3(1024), 0, stream,
                       gt, nsel, ncols, S, Ck, part, mask);
    hipLaunchKernelGGL(k_main, dim3(2048), dim3(256), 0, stream, pred, gt, mask, part);
    hipLaunchKernelGGL(k_pairs, dim3(NN * PB), dim3(256), 0, stream,
                       pred, gt, hcam, ax, ay, xstd, zstd, nsel, ncols, S, Ck, part);
    hipLaunchKernelGGL(k_final, dim3(1), dim3(256), 0, stream, part, out);
}

// Round 10
// 53.922 us; speedup vs baseline: 3.6403x; 1.1939x over previous
//
#include <hip/hip_runtime.h>
#include <math.h>

#define NN 256
#define XX 256
#define TT 3
#define KK 64
#define AA 193          // 3*K+1
#define EPSF 1e-9f
#define NPART 256
#define SBLK 2048       // stream-role blocks
#define PBLK 2048       // pairs-role blocks (8 per n)
#define NBLK (SBLK + PBLK)

// ws layout (bytes):
// [0, 2048)            double part[256]
// [2048, 3072)         int nsel[256]
// [3072, 4096)         int ncols[256]
// [4096, 266240)       int S[256][256]      (full `order` per n)
// [266240, 331776)     int Ck[256][64]      (full `corder` per n)
// [331776, 1118208)    float mask[196608]   (gt_class value per row, 0.0/1.0)

typedef float float4a __attribute__((ext_vector_type(4)));

__device__ __forceinline__ float4a ld4(const float* p) {
    float4a v;
    __builtin_memcpy(&v, p, 16);   // align-4 safe
    return v;
}

// 1024 threads: phase 1 on waves 0-3 (one x per thread), phase 2 on all 16 waves.
__global__ __launch_bounds__(1024) void k_meta(const float* __restrict__ gt,
                                               int* __restrict__ nselArr,
                                               int* __restrict__ ncolsArr,
                                               int* __restrict__ S,
                                               int* __restrict__ Ck,
                                               double* __restrict__ part,
                                               float* __restrict__ mask) {
    int n = blockIdx.x;
    int tid = threadIdx.x;
    int lane = tid & 63;
    int wave = tid >> 6;
    bool isP1 = wave < 4;          // tid < 256, wave-uniform

    // zero the partial-sum buffer (consumers launch after us on the stream)
    if (n == 0 && tid < NPART) part[tid] = 0.0;

    __shared__ int s_S[XX];
    __shared__ int s_cnt[4];
    __shared__ float s_red[16 * 64];
    __shared__ int s_nsel;

    // ---- phase 1a: load gc, write mask, ballot ----
    bool selx = false;
    unsigned long long bal = 0;
    if (isP1) {
        int x = tid;
        size_t rb = ((size_t)(n * XX + x) * TT) * AA;
        float gc0 = gt[rb + 3 * KK];
        float gc1 = gt[rb + AA + 3 * KK];
        float gc2 = gt[rb + 2 * AA + 3 * KK];
        int rowid = (n * XX + x) * TT;
        mask[rowid + 0] = gc0;
        mask[rowid + 1] = gc1;
        mask[rowid + 2] = gc2;
        selx = gc0 > 0.0f;
        bal = __ballot(selx);
        if (lane == 0) s_cnt[wave] = __popcll(bal);
    }
    __syncthreads();

    // ---- phase 1b: stable partition (the `order` array) ----
    if (isP1) {
        int c0 = s_cnt[0], c1 = s_cnt[1], c2 = s_cnt[2], c3 = s_cnt[3];
        int nsel_n = c0 + c1 + c2 + c3;
        int selbase = (wave > 0 ? c0 : 0) + (wave > 1 ? c1 : 0) + (wave > 2 ? c2 : 0);
        unsigned long long ltmask = (1ull << lane) - 1ull;
        int pos;
        if (selx) pos = selbase + __popcll(bal & ltmask);
        else      pos = nsel_n + (64 * wave - selbase) + __popcll((~bal) & ltmask);
        s_S[pos] = tid;
        if (tid == 0) { s_nsel = nsel_n; nselArr[n] = nsel_n; }
    }
    __syncthreads();
    if (tid < XX) S[n * XX + tid] = s_S[tid];

    // ---- phase 2: column sums over selected rows (16 waves) ----
    int nsl = s_nsel;
    float partial = 0.0f;
    for (int i = wave; i < nsl; i += 16) {
        int xs = s_S[i];
        size_t base = ((size_t)(n * XX + xs) * TT) * AA + 2 * KK + lane;
        partial += gt[base] + gt[base + AA] + gt[base + 2 * AA];
    }
    s_red[tid] = partial;
    __syncthreads();

    // ---- phase 3: keep + stable column partition (the `corder` array) ----
    if (tid < KK) {
        float tot = 0.0f;
        #pragma unroll
        for (int w = 0; w < 16; ++w) tot += s_red[tid + 64 * w];
        int nrows = nsl * TT;
        bool keep = (tot >= (float)nrows) || (tid < 5);
        unsigned long long kb = __ballot(keep);
        int nc = __popcll(kb);
        unsigned long long lt = (1ull << tid) - 1ull;
        int cpos = keep ? __popcll(kb & lt) : nc + __popcll((~kb) & lt);
        Ck[n * KK + cpos] = tid;
        if (tid == 0) ncolsArr[n] = nc;
    }
}

// Spatially-partitioned fused kernel (NO fences, NO ticket): even blocks run
// the R9 stream body (loss0/1/2, BW-bound), odd blocks the pairs body
// (loss3/4, latency-bound). Both roles co-resident on every CU -> pairs
// gathers hide in the stream waves' memory-latency slack. Ends with the
// plain part[] atomicAdd only; k_final reduces afterwards.
__global__ __launch_bounds__(256) void k_fused(const float* __restrict__ pred,
                                               const float* __restrict__ gt,
                                               const float* __restrict__ mask,
                                               const float* __restrict__ hcam_arr,
                                               const float* __restrict__ ax,
                                               const float* __restrict__ ay,
                                               const float* __restrict__ xstd,
                                               const float* __restrict__ zstd,
                                               const int* __restrict__ nselArr,
                                               const int* __restrict__ ncolsArr,
                                               const int* __restrict__ S,
                                               const int* __restrict__ Ck,
                                               double* __restrict__ part) {
    int tid = threadIdx.x;
    int lane = tid & 63;
    int wid = tid >> 6;
    int role_pairs = blockIdx.x & 1;
    int idx = blockIdx.x >> 1;          // 0..2047 within each role

    float local = 0.0f;

    if (role_pairs) {
        // ---- pairs role: 8 blocks per n, 32 waves per n ----
        float accp = 0.0f;
        int n = idx >> 3;
        int waveIdx = ((idx & 7) << 2) | wid;          // 0..31
        int nrows = nselArr[n] * TT;
        int ncols = ncolsArr[n];
        int k = Ck[n * KK + lane];
        float inv_h = 1.0f / hcam_arr[n];
        float zs = zstd[k], xs = xstd[k], ayk = ay[k];
        float xstd0 = xstd[0];

        for (int i = 0; i < 24; ++i) {
            int p = i * 32 + waveIdx;                  // covers 0..767
            if (p + 1 >= nrows) break;                 // wave-uniform, monotone
            int r1 = p + 1;
            int x0 = S[n * XX + p / 3];  int t0 = p % 3;
            int x1 = S[n * XX + r1 / 3]; int t1 = r1 % 3;
            size_t b0 = ((size_t)(n * XX + x0) * TT + t0) * AA;
            size_t b1 = ((size_t)(n * XX + x1) * TT + t1) * AA;
            float pz0 = pred[b0 + KK + k], gx0 = gt[b0 + k];
            float pz1 = pred[b1 + KK + k], gx1 = gt[b1 + k];
            float ax0 = ax[x0], ax1 = ax[x1];
            float Z0 = pz0 * zs, Z1 = pz1 * zs;
            float sc0 = 1.0f - Z0 * inv_h, sc1 = 1.0f - Z1 * inv_h;
            float L0 = sc0 * (gx0 * xs + ax0);
            float L1 = sc1 * (gx1 * xs + ax1);
            float Y0 = sc0 * ayk;
            float l00 = gt[b0] * xstd0 + ax0;
            float l01 = gt[b1] * xstd0 + ax1;
            float width0 = fabsf(l01 - l00);

            float lm1 = __shfl_up(L0, 1);
            float ym1 = __shfl_up(Y0, 1);
            float y1v = __shfl(Y0, 1);
            float dYc, lc;
            if (lane == 0) {
                dYc = fabsf(y1v - Y0);
                lc = dYc;
            } else {
                dYc = fabsf(Y0 - ym1);
                float dx = L0 - lm1;
                lc = sqrtf(dx * dx + dYc * dYc);
            }
            float w = fabsf(L1 - L0) * dYc / (lc + EPSF);
            float wm1 = __shfl_up(w, 1);
            float werr = fabsf(w - (lane == 0 ? width0 : wm1));
            float dZ = fabsf(Z1 - Z0);
            if (lane < ncols) accp += werr + dZ;
        }
        local = 5.0f * accp;
    } else {
        // ---- stream role: loss0 + loss1 + loss2 (R9 body) ----
        int sub = lane & 15;        // 16-B chunk within the 256-B field
        int rr = lane >> 4;         // row within group of 4
        int gw = idx * 4 + wid;
        const int NW = SBLK * 4;

        // prefetch all 6 row-mask predicates (mask is 786 KB, L2-resident)
        float mk[6];
        #pragma unroll
        for (int j = 0; j < 6; ++j) mk[j] = mask[4 * (gw + j * NW) + rr];

        float a0 = 0.0f, a12 = 0.0f;
        #pragma unroll
        for (int h = 0; h < 3; ++h) {
            size_t b0 = (size_t)(4 * (gw + (2 * h) * NW) + rr) * AA;
            size_t b1 = (size_t)(4 * (gw + (2 * h + 1) * NW) + rr) * AA;
            bool m0 = mk[2 * h] > 0.0f, m1 = mk[2 * h + 1] > 0.0f;

            float4a pv0 = ld4(pred + b0 + 2 * KK + sub * 4);
            float4a gv0 = ld4(gt   + b0 + 2 * KK + sub * 4);
            float4a pv1 = ld4(pred + b1 + 2 * KK + sub * 4);
            float4a gv1 = ld4(gt   + b1 + 2 * KK + sub * 4);
            float pc0 = pred[b0 + 3 * KK];
            float pc1 = pred[b1 + 3 * KK];
            float4a pX0 = {0,0,0,0}, gX0 = {0,0,0,0}, pX1 = {0,0,0,0}, gX1 = {0,0,0,0};
            if (m0) { pX0 = ld4(pred + b0 + sub * 4); gX0 = ld4(gt + b0 + sub * 4); }
            if (m1) { pX1 = ld4(pred + b1 + sub * 4); gX1 = ld4(gt + b1 + sub * 4); }

            a0 += __logf(gv0.x > 0.0f ? pv0.x + EPSF : 1.0f - pv0.x + EPSF)
                + __logf(gv0.y > 0.0f ? pv0.y + EPSF : 1.0f - pv0.y + EPSF)
                + __logf(gv0.z > 0.0f ? pv0.z + EPSF : 1.0f - pv0.z + EPSF)
                + __logf(gv0.w > 0.0f ? pv0.w + EPSF : 1.0f - pv0.w + EPSF)
                + __logf(gv1.x > 0.0f ? pv1.x + EPSF : 1.0f - pv1.x + EPSF)
                + __logf(gv1.y > 0.0f ? pv1.y + EPSF : 1.0f - pv1.y + EPSF)
                + __logf(gv1.z > 0.0f ? pv1.z + EPSF : 1.0f - pv1.z + EPSF)
                + __logf(gv1.w > 0.0f ? pv1.w + EPSF : 1.0f - pv1.w + EPSF);

            if (sub == 0) {
                a12 -= __logf(m0 ? pc0 + EPSF : 1.0f - pc0 + EPSF);
                a12 -= __logf(m1 ? pc1 + EPSF : 1.0f - pc1 + EPSF);
            }

            if (m0)
                a12 += gv0.x * fabsf(pX0.x - gX0.x) + gv0.y * fabsf(pX0.y - gX0.y)
                     + gv0.z * fabsf(pX0.z - gX0.z) + gv0.w * fabsf(pX0.w - gX0.w);
            if (m1)
                a12 += gv1.x * fabsf(pX1.x - gX1.x) + gv1.y * fabsf(pX1.y - gX1.y)
                     + gv1.z * fabsf(pX1.z - gX1.z) + gv1.w * fabsf(pX1.w - gX1.w);
        }
        local = a12 - a0 * (1.0f / KK);
    }

    // ---- block reduce + one atomic per block ----
    __shared__ float red[256];
    red[tid] = local;
    __syncthreads();
    for (int s = 128; s > 0; s >>= 1) {
        if (tid < s) red[tid] += red[tid + s];
        __syncthreads();
    }
    if (tid == 0) atomicAdd(&part[blockIdx.x & (NPART - 1)], (double)red[0]);
}

__global__ __launch_bounds__(256) void k_final(const double* __restrict__ part,
                                               float* __restrict__ out) {
    int tid = threadIdx.x;
    __shared__ double red[256];
    red[tid] = part[tid];
    __syncthreads();
    for (int s = 128; s > 0; s >>= 1) {
        if (tid < s) red[tid] += red[tid + s];
        __syncthreads();
    }
    if (tid == 0) out[0] = (float)red[0];
}

extern "C" void kernel_launch(void* const* d_in, const int* in_sizes, int n_in,
                              void* d_out, int out_size, void* d_ws, size_t ws_size,
                              hipStream_t stream) {
    const float* pred = (const float*)d_in[0];
    const float* gt   = (const float*)d_in[1];
    const float* hcam = (const float*)d_in[2];
    const float* ax   = (const float*)d_in[3];
    const float* ay   = (const float*)d_in[4];
    const float* xstd = (const float*)d_in[5];
    const float* zstd = (const float*)d_in[6];
    float* out = (float*)d_out;

    char* ws = (char*)d_ws;
    double* part = (double*)ws;
    int* nsel   = (int*)(ws + 2048);
    int* ncols  = (int*)(ws + 3072);
    int* S      = (int*)(ws + 4096);
    int* Ck     = (int*)(ws + 266240);
    float* mask = (float*)(ws + 331776);

    hipLaunchKernelGGL(k_meta, dim3(NN), dim3(1024), 0, stream,
                       gt, nsel, ncols, S, Ck, part, mask);
    hipLaunchKernelGGL(k_fused, dim3(NBLK), dim3(256), 0, stream,
                       pred, gt, mask, hcam, ax, ay, xstd, zstd,
                       nsel, ncols, S, Ck, part);
    hipLaunchKernelGGL(k_final, dim3(1), dim3(256), 0, stream, part, out);
}

// Round 11
// 52.849 us; speedup vs baseline: 3.7142x; 1.0203x over previous
//
#include <hip/hip_runtime.h>
#include <math.h>

#define NN 256
#define XX 256
#define TT 3
#define KK 64
#define AA 193          // 3*K+1
#define EPSF 1e-9f
#define NPART 256
#define SBLK 2048       // stream-role blocks
#define PBLK 2048       // pairs-role blocks (8 per n)
#define NBLK (SBLK + PBLK)

// ws layout (bytes):
// [0, 2048)            double part[256]
// [2048, 3072)         int nsel[256]
// [3072, 4096)         int ncols[256]
// [4096, 266240)       int S[256][256]      (full `order` per n)
// [266240, 331776)     int Ck[256][64]      (full `corder` per n)
// [331776, 1118208)    float mask[196608]   (gt_class value per row, 0.0/1.0)

typedef float float4a __attribute__((ext_vector_type(4)));

__device__ __forceinline__ float4a ld4(const float* p) {
    float4a v;
    __builtin_memcpy(&v, p, 16);   // align-4 safe
    return v;
}

// 1024 threads: phase 1 on waves 0-3 (one x per thread), phase 2 on all 16 waves.
__global__ __launch_bounds__(1024) void k_meta(const float* __restrict__ gt,
                                               int* __restrict__ nselArr,
                                               int* __restrict__ ncolsArr,
                                               int* __restrict__ S,
                                               int* __restrict__ Ck,
                                               double* __restrict__ part,
                                               float* __restrict__ mask) {
    int n = blockIdx.x;
    int tid = threadIdx.x;
    int lane = tid & 63;
    int wave = tid >> 6;
    bool isP1 = wave < 4;          // tid < 256, wave-uniform

    // zero the partial-sum buffer (consumers launch after us on the stream)
    if (n == 0 && tid < NPART) part[tid] = 0.0;

    __shared__ int s_S[XX];
    __shared__ int s_cnt[4];
    __shared__ float s_red[16 * 64];
    __shared__ int s_nsel;

    // ---- phase 1a: load gc, write mask, ballot ----
    bool selx = false;
    unsigned long long bal = 0;
    if (isP1) {
        int x = tid;
        size_t rb = ((size_t)(n * XX + x) * TT) * AA;
        float gc0 = gt[rb + 3 * KK];
        float gc1 = gt[rb + AA + 3 * KK];
        float gc2 = gt[rb + 2 * AA + 3 * KK];
        int rowid = (n * XX + x) * TT;
        mask[rowid + 0] = gc0;
        mask[rowid + 1] = gc1;
        mask[rowid + 2] = gc2;
        selx = gc0 > 0.0f;
        bal = __ballot(selx);
        if (lane == 0) s_cnt[wave] = __popcll(bal);
    }
    __syncthreads();

    // ---- phase 1b: stable partition (the `order` array) ----
    if (isP1) {
        int c0 = s_cnt[0], c1 = s_cnt[1], c2 = s_cnt[2], c3 = s_cnt[3];
        int nsel_n = c0 + c1 + c2 + c3;
        int selbase = (wave > 0 ? c0 : 0) + (wave > 1 ? c1 : 0) + (wave > 2 ? c2 : 0);
        unsigned long long ltmask = (1ull << lane) - 1ull;
        int pos;
        if (selx) pos = selbase + __popcll(bal & ltmask);
        else      pos = nsel_n + (64 * wave - selbase) + __popcll((~bal) & ltmask);
        s_S[pos] = tid;
        if (tid == 0) { s_nsel = nsel_n; nselArr[n] = nsel_n; }
    }
    __syncthreads();
    if (tid < XX) S[n * XX + tid] = s_S[tid];

    // ---- phase 2: column sums over selected rows (16 waves) ----
    int nsl = s_nsel;
    float partial = 0.0f;
    for (int i = wave; i < nsl; i += 16) {
        int xs = s_S[i];
        size_t base = ((size_t)(n * XX + xs) * TT) * AA + 2 * KK + lane;
        partial += gt[base] + gt[base + AA] + gt[base + 2 * AA];
    }
    s_red[tid] = partial;
    __syncthreads();

    // ---- phase 3: keep + stable column partition (the `corder` array) ----
    if (tid < KK) {
        float tot = 0.0f;
        #pragma unroll
        for (int w = 0; w < 16; ++w) tot += s_red[tid + 64 * w];
        int nrows = nsl * TT;
        bool keep = (tot >= (float)nrows) || (tid < 5);
        unsigned long long kb = __ballot(keep);
        int nc = __popcll(kb);
        unsigned long long lt = (1ull << tid) - 1ull;
        int cpos = keep ? __popcll(kb & lt) : nc + __popcll((~kb) & lt);
        Ck[n * KK + cpos] = tid;
        if (tid == 0) ncolsArr[n] = nc;
    }
}

// Spatially-partitioned fused kernel (NO fences, NO ticket): even blocks run
// the stream body (loss0/1/2, BW-bound), odd blocks the pairs body (loss3/4,
// latency-bound). BCE logs folded via log(prod) identity: select values are
// in (0.01, 1.0) by construction -> 8-term product >= 1e-16, no underflow.
__global__ __launch_bounds__(256) void k_fused(const float* __restrict__ pred,
                                               const float* __restrict__ gt,
                                               const float* __restrict__ mask,
                                               const float* __restrict__ hcam_arr,
                                               const float* __restrict__ ax,
                                               const float* __restrict__ ay,
                                               const float* __restrict__ xstd,
                                               const float* __restrict__ zstd,
                                               const int* __restrict__ nselArr,
                                               const int* __restrict__ ncolsArr,
                                               const int* __restrict__ S,
                                               const int* __restrict__ Ck,
                                               double* __restrict__ part) {
    int tid = threadIdx.x;
    int lane = tid & 63;
    int wid = tid >> 6;
    int role_pairs = blockIdx.x & 1;
    int idx = blockIdx.x >> 1;          // 0..2047 within each role

    float local = 0.0f;

    if (role_pairs) {
        // ---- pairs role: 8 blocks per n, 32 waves per n ----
        float accp = 0.0f;
        int n = idx >> 3;
        int waveIdx = ((idx & 7) << 2) | wid;          // 0..31
        int nrows = nselArr[n] * TT;
        int ncols = ncolsArr[n];
        int k = Ck[n * KK + lane];
        float inv_h = 1.0f / hcam_arr[n];
        float zs = zstd[k], xs = xstd[k], ayk = ay[k];
        float xstd0 = xstd[0];

        for (int i = 0; i < 24; ++i) {
            int p = i * 32 + waveIdx;                  // covers 0..767
            if (p + 1 >= nrows) break;                 // wave-uniform, monotone
            int r1 = p + 1;
            int x0 = S[n * XX + p / 3];  int t0 = p % 3;
            int x1 = S[n * XX + r1 / 3]; int t1 = r1 % 3;
            size_t b0 = ((size_t)(n * XX + x0) * TT + t0) * AA;
            size_t b1 = ((size_t)(n * XX + x1) * TT + t1) * AA;
            float pz0 = pred[b0 + KK + k], gx0 = gt[b0 + k];
            float pz1 = pred[b1 + KK + k], gx1 = gt[b1 + k];
            float ax0 = ax[x0], ax1 = ax[x1];
            float Z0 = pz0 * zs, Z1 = pz1 * zs;
            float sc0 = 1.0f - Z0 * inv_h, sc1 = 1.0f - Z1 * inv_h;
            float L0 = sc0 * (gx0 * xs + ax0);
            float L1 = sc1 * (gx1 * xs + ax1);
            float Y0 = sc0 * ayk;
            float l00 = gt[b0] * xstd0 + ax0;
            float l01 = gt[b1] * xstd0 + ax1;
            float width0 = fabsf(l01 - l00);

            float lm1 = __shfl_up(L0, 1);
            float ym1 = __shfl_up(Y0, 1);
            float y1v = __shfl(Y0, 1);
            float dYc, lc;
            if (lane == 0) {
                dYc = fabsf(y1v - Y0);
                lc = dYc;
            } else {
                dYc = fabsf(Y0 - ym1);
                float dx = L0 - lm1;
                lc = sqrtf(dx * dx + dYc * dYc);
            }
            float w = fabsf(L1 - L0) * dYc / (lc + EPSF);
            float wm1 = __shfl_up(w, 1);
            float werr = fabsf(w - (lane == 0 ? width0 : wm1));
            float dZ = fabsf(Z1 - Z0);
            if (lane < ncols) accp += werr + dZ;
        }
        local = 5.0f * accp;
    } else {
        // ---- stream role: loss0 + loss1 + loss2 ----
        int sub = lane & 15;        // 16-B chunk within the 256-B field
        int rr = lane >> 4;         // row within group of 4
        int gw = idx * 4 + wid;
        const int NW = SBLK * 4;

        // prefetch all 6 row-mask predicates (mask is 786 KB, L2-resident)
        float mk[6];
        #pragma unroll
        for (int j = 0; j < 6; ++j) mk[j] = mask[4 * (gw + j * NW) + rr];

        float a0 = 0.0f, a12 = 0.0f;
        #pragma unroll
        for (int h = 0; h < 3; ++h) {
            size_t b0 = (size_t)(4 * (gw + (2 * h) * NW) + rr) * AA;
            size_t b1 = (size_t)(4 * (gw + (2 * h + 1) * NW) + rr) * AA;
            bool m0 = mk[2 * h] > 0.0f, m1 = mk[2 * h + 1] > 0.0f;

            float4a pv0 = ld4(pred + b0 + 2 * KK + sub * 4);
            float4a gv0 = ld4(gt   + b0 + 2 * KK + sub * 4);
            float4a pv1 = ld4(pred + b1 + 2 * KK + sub * 4);
            float4a gv1 = ld4(gt   + b1 + 2 * KK + sub * 4);
            float pc0 = pred[b0 + 3 * KK];
            float pc1 = pred[b1 + 3 * KK];
            float4a pX0 = {0,0,0,0}, gX0 = {0,0,0,0}, pX1 = {0,0,0,0}, gX1 = {0,0,0,0};
            if (m0) { pX0 = ld4(pred + b0 + sub * 4); gX0 = ld4(gt + b0 + sub * 4); }
            if (m1) { pX1 = ld4(pred + b1 + sub * 4); gX1 = ld4(gt + b1 + sub * 4); }

            // BCE select values; all in (0.01, 1.0) -> product of 8 safe
            float s0 = gv0.x > 0.0f ? pv0.x + EPSF : 1.0f - pv0.x + EPSF;
            float s1 = gv0.y > 0.0f ? pv0.y + EPSF : 1.0f - pv0.y + EPSF;
            float s2 = gv0.z > 0.0f ? pv0.z + EPSF : 1.0f - pv0.z + EPSF;
            float s3 = gv0.w > 0.0f ? pv0.w + EPSF : 1.0f - pv0.w + EPSF;
            float s4 = gv1.x > 0.0f ? pv1.x + EPSF : 1.0f - pv1.x + EPSF;
            float s5 = gv1.y > 0.0f ? pv1.y + EPSF : 1.0f - pv1.y + EPSF;
            float s6 = gv1.z > 0.0f ? pv1.z + EPSF : 1.0f - pv1.z + EPSF;
            float s7 = gv1.w > 0.0f ? pv1.w + EPSF : 1.0f - pv1.w + EPSF;
            a0 += __logf(((s0 * s1) * (s2 * s3)) * ((s4 * s5) * (s6 * s7)));

            if (sub == 0) {
                float c0 = m0 ? pc0 + EPSF : 1.0f - pc0 + EPSF;
                float c1 = m1 ? pc1 + EPSF : 1.0f - pc1 + EPSF;
                a12 -= __logf(c0 * c1);
            }

            if (m0)
                a12 += gv0.x * fabsf(pX0.x - gX0.x) + gv0.y * fabsf(pX0.y - gX0.y)
                     + gv0.z * fabsf(pX0.z - gX0.z) + gv0.w * fabsf(pX0.w - gX0.w);
            if (m1)
                a12 += gv1.x * fabsf(pX1.x - gX1.x) + gv1.y * fabsf(pX1.y - gX1.y)
                     + gv1.z * fabsf(pX1.z - gX1.z) + gv1.w * fabsf(pX1.w - gX1.w);
        }
        local = a12 - a0 * (1.0f / KK);
    }

    // ---- wave reduce (no barriers) + cross-wave + one atomic per block ----
    #pragma unroll
    for (int d = 32; d > 0; d >>= 1) local += __shfl_xor(local, d);

    __shared__ float s_w[4];
    if (lane == 0) s_w[wid] = local;
    __syncthreads();
    if (tid == 0) {
        float tot = s_w[0] + s_w[1] + s_w[2] + s_w[3];
        atomicAdd(&part[blockIdx.x & (NPART - 1)], (double)tot);
    }
}

__global__ __launch_bounds__(256) void k_final(const double* __restrict__ part,
                                               float* __restrict__ out) {
    int tid = threadIdx.x;
    __shared__ double red[256];
    red[tid] = part[tid];
    __syncthreads();
    for (int s = 128; s > 0; s >>= 1) {
        if (tid < s) red[tid] += red[tid + s];
        __syncthreads();
    }
    if (tid == 0) out[0] = (float)red[0];
}

extern "C" void kernel_launch(void* const* d_in, const int* in_sizes, int n_in,
                              void* d_out, int out_size, void* d_ws, size_t ws_size,
                              hipStream_t stream) {
    const float* pred = (const float*)d_in[0];
    const float* gt   = (const float*)d_in[1];
    const float* hcam = (const float*)d_in[2];
    const float* ax   = (const float*)d_in[3];
    const float* ay   = (const float*)d_in[4];
    const float* xstd = (const float*)d_in[5];
    const float* zstd = (const float*)d_in[6];
    float* out = (float*)d_out;

    char* ws = (char*)d_ws;
    double* part = (double*)ws;
    int* nsel   = (int*)(ws + 2048);
    int* ncols  = (int*)(ws + 3072);
    int* S      = (int*)(ws + 4096);
    int* Ck     = (int*)(ws + 266240);
    float* mask = (float*)(ws + 331776);

    hipLaunchKernelGGL(k_meta, dim3(NN), dim3(1024), 0, stream,
                       gt, nsel, ncols, S, Ck, part, mask);
    hipLaunchKernelGGL(k_fused, dim3(NBLK), dim3(256), 0, stream,
                       pred, gt, mask, hcam, ax, ay, xstd, zstd,
                       nsel, ncols, S, Ck, part);
    hipLaunchKernelGGL(k_final, dim3(1), dim3(256), 0, stream, part, out);
}